// Round 2
// baseline (472.798 us; speedup 1.0000x reference)
//
#include <hip/hip_runtime.h>
#include <hip/hip_bf16.h>
#include <math.h>

#define BATCH  8
#define NHEADS 8
#define KW     31
#define W      16384

// ---- workspace byte offsets ----
// floats at base: qWk [256][8] (2048 f), qWk_b [8], rpe_exp [8][31]
#define WS_QWKB 2048
#define WS_RPE  2056
#define OFF_WVH 9216                       // Wv bf16 [256][256]  (131072 B)
#define OFF_WOH (OFF_WVH + 131072)         // Wo bf16 [256][256]
#define OFF_CE  (OFF_WOH + 131072)         // cost_exp fp32 [NB][8][W]
// runtime-sized after OFF_CE:  vc fp32 [NB][W][256], u bf16 [NB][W][2][256]

typedef __attribute__((ext_vector_type(8))) short  short8;
typedef __attribute__((ext_vector_type(4))) float  f32x4;

__device__ __forceinline__ float f4c(const float4& v, int i) {
  switch (i) { case 0: return v.x; case 1: return v.y; case 2: return v.z; default: return v.w; }
}
__device__ __forceinline__ unsigned short f2bf(float f) {
  union { __hip_bfloat16 h; unsigned short u; } cv; cv.h = __float2bfloat16(f); return cv.u;
}
__device__ __forceinline__ float bf2f(unsigned short u) {
  union { __hip_bfloat16 h; unsigned short u; } cv; cv.u = u; return __bfloat162float(cv.h);
}

// ---------------------------------------------------------------- prep ------
// block 0: qWk [256][8], qWk_b[8], rpe_exp; blocks 1-4: Wv->bf16; 5-8: Wo->bf16
__global__ __launch_bounds__(256) void prep_kernel(
    const float* __restrict__ query, const float* __restrict__ Wk,
    const float* __restrict__ Wkb, const float* __restrict__ rpe,
    const float* __restrict__ Wv, const float* __restrict__ Wo,
    float* __restrict__ ws, unsigned short* __restrict__ WvH,
    unsigned short* __restrict__ WoH) {
  int t = threadIdx.x, bid = blockIdx.x;
  if (bid == 0) {
    __shared__ float q_l[256];
    float qv = query[t];
    float ss = qv * qv;
    #pragma unroll
    for (int m = 16; m >= 1; m >>= 1) ss += __shfl_xor(ss, m, 32);
    qv = qv / (sqrtf(ss) + 1e-6f) * 0.17677669529663687f;  // /(norm+1e-6)/sqrt(32)
    q_l[t] = qv;
    __syncthreads();
    const float* wr = Wk + (size_t)t * 256;
    #pragma unroll
    for (int h = 0; h < 8; ++h) {
      float s = 0.f;
      #pragma unroll
      for (int d = 0; d < 32; ++d) s = fmaf(q_l[h*32 + d], wr[h*32 + d], s);
      ws[t*8 + h] = s;
    }
    float pb = Wkb[t] * q_l[t];
    #pragma unroll
    for (int m = 16; m >= 1; m >>= 1) pb += __shfl_xor(pb, m, 32);
    if ((t & 31) == 0) ws[WS_QWKB + (t >> 5)] = pb;
    if (t < NHEADS * KW) ws[WS_RPE + t] = __expf(rpe[t]);
  } else {
    const float* src = (bid <= 4) ? Wv : Wo;
    unsigned short* dst = (bid <= 4) ? WvH : WoH;
    int seg = (bid - 1) & 3;
    int base4 = seg * 4096;   // float4 index base (16384 floats per segment)
    #pragma unroll
    for (int it = 0; it < 16; ++it) {
      int i4 = base4 + t + 256 * it;
      float4 v = ((const float4*)src)[i4];
      ushort4 o;
      o.x = f2bf(v.x); o.y = f2bf(v.y); o.z = f2bf(v.z); o.w = f2bf(v.w);
      ((ushort4*)dst)[i4] = o;
    }
  }
}

// ---------------------------------------------- K2: fused transpose+cost+V --
// 512 threads (8 waves), 64-w tile. LDS 78,848 B -> 2 blocks/CU (16 waves).
// P1 transpose x->LDS fp32; P2 cost partials + in-place hi/lo bf16 split;
// P3 exp(cost); P4 MFMA v=Wv.x; P5 vc = ce*(v+bias) -> linear coalesced store.
__global__ __launch_bounds__(512, 4) void xv_kernel(
    const float* __restrict__ x, const float* __restrict__ wsf,
    const unsigned short* __restrict__ A,   // WvH bf16 [256][256]
    const float* __restrict__ bias,         // to_v bias
    float* __restrict__ ceout, float* __restrict__ vcout, int b0) {
  __shared__ float xs[64 * 260];    // 66,560 B; row w = 1040 B:
                                    //   phase A: 256 fp32 chans
                                    //   phase B: 256 hi bf16 | 256 lo bf16 (in place)
  __shared__ float cbuf[4 * 576];   // 9,216 B: 4-wave partial rounds, pitch 9
  __shared__ float ceL[512];        // 2,048 B
  __shared__ float biasL[256];      // 1,024 B

  int t = threadIdx.x;
  int bb = blockIdx.y, b = b0 + bb;
  int w0 = blockIdx.x * 64;
  if (t < 256) biasL[t] = bias[t];

  // P1: load x[D][w] tiles, 4x4 register transpose, write xs[w][D] fp32
  {
    int tt = t & 255, db2 = t >> 8;
    int rr = tt >> 4, c2 = tt & 15;
    #pragma unroll
    for (int dd = 0; dd < 2; ++dd) {
      int db = db2 * 2 + dd;
      float4 v0 = *(const float4*)(x + ((size_t)b*256 + db*64 + rr*4 + 0)*W + w0 + c2*4);
      float4 v1 = *(const float4*)(x + ((size_t)b*256 + db*64 + rr*4 + 1)*W + w0 + c2*4);
      float4 v2 = *(const float4*)(x + ((size_t)b*256 + db*64 + rr*4 + 2)*W + w0 + c2*4);
      float4 v3 = *(const float4*)(x + ((size_t)b*256 + db*64 + rr*4 + 3)*W + w0 + c2*4);
      #pragma unroll
      for (int i = 0; i < 4; ++i) {
        float4 tv = make_float4(f4c(v0,i), f4c(v1,i), f4c(v2,i), f4c(v3,i));
        *(float4*)&xs[(c2*4 + i)*260 + db*64 + rr*4] = tv;
      }
    }
  }
  __syncthreads();

  int w = t & 63, q = t >> 6;                 // wave-uniform q (0..7)
  int qu = __builtin_amdgcn_readfirstlane(q); // scalar qWk addressing

  // P2a: pull this thread's 32-chan run into regs, accumulate cost partials
  f32x4 xr[8];
  {
    const float* xrow = &xs[w*260 + qu*32];
    #pragma unroll
    for (int i = 0; i < 8; ++i) xr[i] = *(const f32x4*)(xrow + 4*i);
    float ca[8] = {0,0,0,0,0,0,0,0};
    const float* qkb = wsf + (size_t)qu*256;  // qWk[D][8], D base qu*32
    #pragma unroll
    for (int k4 = 0; k4 < 8; ++k4) {
      const float* qr = qkb + k4*32;
      #pragma unroll
      for (int e = 0; e < 4; ++e) {
        #pragma unroll
        for (int h = 0; h < 8; ++h)
          ca[h] = fmaf(xr[k4][e], qr[e*8 + h], ca[h]);
      }
    }
    if (q < 4) {
      #pragma unroll
      for (int h = 0; h < 8; ++h) cbuf[q*576 + w*9 + h] = ca[h];
    } else {
      // stash for round B (keep in registers until after sync)
      #pragma unroll
      for (int h = 0; h < 8; ++h) xr[h & 7][0] = xr[h & 7][0];  // no-op keep
      // round-B write happens below; ca must survive: recompute-free via regs
      // (ca is still live here; written after next barrier)
      // fallthrough with ca live
      #pragma unroll
      for (int h = 0; h < 8; ++h) { /* keep ca live */ asm volatile("" :: "v"(ca[h])); }
    }
    __syncthreads();   // xs fp32 reads done; cbuf round A visible

    // P2b: in-place hi/lo bf16 split (this thread's 32 chans of row w)
    {
      unsigned short* hrow = (unsigned short*)xs + w*520 + qu*32;
      #pragma unroll
      for (int kc = 0; kc < 4; ++kc) {
        short8 hs, ls;
        #pragma unroll
        for (int e = 0; e < 4; ++e) {
          float a0 = xr[2*kc][e], a1 = xr[2*kc+1][e];
          unsigned short h0 = f2bf(a0), h1 = f2bf(a1);
          hs[e]   = (short)h0;  hs[e+4] = (short)h1;
          ls[e]   = (short)f2bf(a0 - bf2f(h0));
          ls[e+4] = (short)f2bf(a1 - bf2f(h1));
        }
        *(short8*)(hrow + 8*kc)       = hs;
        *(short8*)(hrow + 256 + 8*kc) = ls;
      }
    }
    // reduce round A while hi/lo writes are in flight
    float acc0;
    {
      int hR = t >> 6 & 7, wR = t & 63;   // this thread's (h,w) for ce
      acc0 = cbuf[0*576 + wR*9 + hR] + cbuf[1*576 + wR*9 + hR]
           + cbuf[2*576 + wR*9 + hR] + cbuf[3*576 + wR*9 + hR];
    }
    __syncthreads();   // round-A reads done
    if (q >= 4) {
      #pragma unroll
      for (int h = 0; h < 8; ++h) cbuf[(q-4)*576 + w*9 + h] = ca[h];
    }
    __syncthreads();   // round B visible

    // P3: final reduce, exp, -> ceL + global ce
    {
      int hR = t >> 6 & 7, wR = t & 63;
      float sum = acc0 + cbuf[0*576 + wR*9 + hR] + cbuf[1*576 + wR*9 + hR]
                + cbuf[2*576 + wR*9 + hR] + cbuf[3*576 + wR*9 + hR]
                + wsf[WS_QWKB + hR];
      float ce = __expf(sum);
      ceL[hR*64 + wR] = ce;
      ceout[((size_t)bb*8 + hR)*W + w0 + wR] = ce;
    }
  }
  __syncthreads();

  // P4: MFMA GEMM  v[256 o][64 w] = Wv . x  (hi + lo); wave wid owns o-rows
  // 32wid..32wid+31 (exactly head wid)
  int wid = t >> 6, quad = (t >> 4) & 3, m = t & 15;
  f32x4 acc[2][4];
  #pragma unroll
  for (int j = 0; j < 2; ++j)
    #pragma unroll
    for (int c = 0; c < 4; ++c) acc[j][c] = (f32x4){0.f, 0.f, 0.f, 0.f};

  const unsigned short* xsu = (const unsigned short*)xs;
  #pragma unroll
  for (int kk = 0; kk < 8; ++kk) {
    int ko = kk*32 + quad*8;
    short8 a0 = *(const short8*)(A + (size_t)(32*wid + m)*256 + ko);
    short8 a1 = *(const short8*)(A + (size_t)(32*wid + 16 + m)*256 + ko);
    #pragma unroll
    for (int c = 0; c < 4; ++c) {
      int rw = 16*c + m;
      short8 bh = *(const short8*)(xsu + rw*520 + ko);
      short8 bl = *(const short8*)(xsu + rw*520 + 256 + ko);
      acc[0][c] = __builtin_amdgcn_mfma_f32_16x16x32_bf16(a0, bh, acc[0][c], 0, 0, 0);
      acc[0][c] = __builtin_amdgcn_mfma_f32_16x16x32_bf16(a0, bl, acc[0][c], 0, 0, 0);
      acc[1][c] = __builtin_amdgcn_mfma_f32_16x16x32_bf16(a1, bh, acc[1][c], 0, 0, 0);
      acc[1][c] = __builtin_amdgcn_mfma_f32_16x16x32_bf16(a1, bl, acc[1][c], 0, 0, 0);
    }
  }
  __syncthreads();   // B-reads of xs done before epilogue reuses it

  // P5: vc = ce[h][w] * (v + bias) -> xs [w][256 o] pitch 260
  #pragma unroll
  for (int j = 0; j < 2; ++j) {
    int ob = 32*wid + 16*j + 4*quad;
    #pragma unroll
    for (int c = 0; c < 4; ++c) {
      int wc = 16*c + m;
      float ce = ceL[wid*64 + wc];   // head == wid
      f32x4 r;
      #pragma unroll
      for (int i = 0; i < 4; ++i) r[i] = (acc[j][c][i] + biasL[ob + i]) * ce;
      *(f32x4*)(xs + wc*260 + ob) = r;
    }
  }
  __syncthreads();
  // linear coalesced copy-out: wave writes contiguous 1 KiB per instruction
  {
    float* vg = vcout + ((size_t)bb*W + w0)*256;
    #pragma unroll
    for (int it = 0; it < 8; ++it) {
      int idx = t + 512*it;                 // 4096 x 16B = 64 KiB
      int row = idx >> 6, c4 = (idx & 63)*4;
      f32x4 v = *(const f32x4*)(xs + row*260 + c4);
      *(f32x4*)(vg + (size_t)idx*4) = v;
    }
  }
}

// ------------------------------------------------------- K4: conv -----------
// depthwise K=31 windowed sums of vc and ce; u = sum_v/sum_c -> bf16 hi/lo
// quarter-chan tiles (64 chans): LDS ~27 KB -> 4 blocks/CU
__global__ __launch_bounds__(256, 4) void conv_kernel(
    const float* __restrict__ vc, const float* __restrict__ costexp,
    const float* __restrict__ rpe_ws, unsigned short* __restrict__ u) {
  __shared__ float vcl[94 * 68];    // [w'][64 d] fp32, pitch 68  (25,568 B)
  __shared__ float cel[2 * 96];     // ce halo (2 heads)
  __shared__ float rcl[2 * 64];     // 1/sum_c
  __shared__ float rpel[2 * 32];

  int t = threadIdx.x;
  int qd = blockIdx.y, bb = blockIdx.z;     // qd: 64-chan quarter (0..3)
  int w0 = blockIdx.x * 64;
  int h0 = qd * 2;                          // first head of this quarter

  if (t < 64) rpel[t] = ((t & 31) < KW) ? rpe_ws[(h0 + (t >> 5))*KW + (t & 31)] : 0.f;
  // stage ce halo [2][96]
  if (t < 192) {
    int h2 = t / 96, c = t % 96;
    int gw = w0 - 15 + c;
    cel[t] = (c < 94 && gw >= 0 && gw < W) ? costexp[((size_t)bb*8 + h0 + h2)*W + gw] : 0.f;
  }
  // stage vc tile [94][64]
  #pragma unroll
  for (int it = 0; it < 6; ++it) {
    int idx = t + 256*it;
    int r = idx >> 4, c4 = (idx & 15)*4;
    if (r < 94) {
      int gw = w0 - 15 + r;
      float4 v = make_float4(0.f, 0.f, 0.f, 0.f);
      if (gw >= 0 && gw < W)
        v = *(const float4*)(vc + ((size_t)bb*W + gw)*256 + qd*64 + c4);
      *(float4*)&vcl[r*68 + c4] = v;
    }
  }
  __syncthreads();

  // rc = 1/sum_c for (2 heads, 64 w)
  if (t < 128) {
    int h2 = t >> 6, w = t & 63;
    float acc = 0.f;
    #pragma unroll
    for (int k = 0; k < KW; ++k) acc = fmaf(rpel[h2*32 + k], cel[h2*96 + w + k], acc);
    rcl[h2*64 + w] = 1.0f / acc;
  }
  __syncthreads();

  int p = t & 31, g = t >> 5;     // p: chan pair (2p,2p+1); g: 8-w output group
  int h2 = p >> 4;                // head-in-block of this chan pair
  float rp[KW];
  #pragma unroll
  for (int k = 0; k < KW; ++k) rp[k] = rpel[h2*32 + k];

  float ax[8], ay[8];
  #pragma unroll
  for (int i = 0; i < 8; ++i) { ax[i] = 0.f; ay[i] = 0.f; }
  #pragma unroll
  for (int s = 0; s < 38; ++s) {
    float2 v = *(const float2*)&vcl[(8*g + s)*68 + 2*p];
    #pragma unroll
    for (int i = 0; i < 8; ++i) {
      int k = s - i;
      if (k >= 0 && k < KW) {
        ax[i] = fmaf(rp[k], v.x, ax[i]);
        ay[i] = fmaf(rp[k], v.y, ay[i]);
      }
    }
  }
  #pragma unroll
  for (int i = 0; i < 8; ++i) {
    int o = 8*g + i;
    float rc = rcl[h2*64 + o];
    float ux = ax[i] * rc, uy = ay[i] * rc;
    unsigned short hx = f2bf(ux), hy = f2bf(uy);
    unsigned short lx = f2bf(ux - bf2f(hx)), ly = f2bf(uy - bf2f(hy));
    unsigned short* ud = u + ((size_t)bb*W + w0 + o)*512 + qd*64 + 2*p;
    ushort2 hvv; hvv.x = hx; hvv.y = hy;
    ushort2 lvv; lvv.x = lx; lvv.y = ly;
    *(ushort2*)(ud)       = hvv;
    *(ushort2*)(ud + 256) = lvv;
  }
}

// ------------------------------------------------- K5: MFMA GEMM (out) ------
// out[o][w] = Wo(bf16 256x256) . u(hi+lo bf16, [w][hi256|lo256]) + bias
// hi/lo planes staged sequentially (LDS ~35 KB -> 4 blocks/CU);
// fragment-direct global stores (no epilogue LDS buffer).
__global__ __launch_bounds__(256, 4) void gemm_out(
    const unsigned short* __restrict__ A, const float* __restrict__ bias,
    const unsigned short* __restrict__ u, float* __restrict__ outp, int b0) {
  __shared__ unsigned short bs[64 * 264];   // 33,792 B (one plane, pitch 264)
  __shared__ float biasL[256];

  int t = threadIdx.x;
  int bb = blockIdx.y;
  int w0 = blockIdx.x * 64;
  biasL[t] = bias[t];

  int wid = t >> 6, quad = (t >> 4) & 3, m = t & 15;
  f32x4 acc[4][4];
  #pragma unroll
  for (int j = 0; j < 4; ++j)
    #pragma unroll
    for (int c = 0; c < 4; ++c) acc[j][c] = (f32x4){0.f, 0.f, 0.f, 0.f};

  const unsigned short* src = u + ((size_t)bb*W + w0)*512;
  #pragma unroll
  for (int pass = 0; pass < 2; ++pass) {
    // stage one plane: 64 rows x 512 B
    #pragma unroll
    for (int it = 0; it < 8; ++it) {
      int idx = t + 256*it;
      int row = idx >> 5, cc = (idx & 31)*8;
      *(short8*)(bs + row*264 + cc) =
          *(const short8*)(src + (size_t)row*512 + pass*256 + cc);
    }
    __syncthreads();
    #pragma unroll
    for (int kk = 0; kk < 8; ++kk) {
      int ko = kk*32 + quad*8;
      short8 a[4];
      #pragma unroll
      for (int j = 0; j < 4; ++j)
        a[j] = *(const short8*)(A + (size_t)(64*wid + 16*j + m)*256 + ko);
      #pragma unroll
      for (int c = 0; c < 4; ++c) {
        short8 bv = *(const short8*)(bs + (16*c + m)*264 + ko);
        #pragma unroll
        for (int j = 0; j < 4; ++j)
          acc[j][c] = __builtin_amdgcn_mfma_f32_16x16x32_bf16(a[j], bv, acc[j][c], 0, 0, 0);
      }
    }
    __syncthreads();   // done reading this plane before restage
  }

  // epilogue: direct stores; per instr a wave covers 4 rows x 64 B
  float* og = outp + (size_t)(b0 + bb)*256*W;
  #pragma unroll
  for (int j = 0; j < 4; ++j) {
    int ob = 64*wid + 16*j + 4*quad;
    #pragma unroll
    for (int c = 0; c < 4; ++c) {
      int w = w0 + 16*c + m;
      #pragma unroll
      for (int i = 0; i < 4; ++i)
        og[(size_t)(ob + i)*W + w] = acc[j][c][i] + biasL[ob + i];
    }
  }
}

// ---------------------------------------------------------------- launch ----
extern "C" void kernel_launch(void* const* d_in, const int* in_sizes, int n_in,
                              void* d_out, int out_size, void* d_ws, size_t ws_size,
                              hipStream_t stream) {
  const float* x     = (const float*)d_in[0];
  const float* query = (const float*)d_in[1];
  const float* Wk    = (const float*)d_in[2];
  const float* Wkb   = (const float*)d_in[3];
  const float* rpe   = (const float*)d_in[4];
  const float* Wv    = (const float*)d_in[5];
  const float* tvb   = (const float*)d_in[6];
  const float* Wo    = (const float*)d_in[7];
  const float* tob   = (const float*)d_in[8];
  float* out = (float*)d_out;
  char* wsb  = (char*)d_ws;
  float* wsf = (float*)d_ws;

  unsigned short* WvH = (unsigned short*)(wsb + OFF_WVH);
  unsigned short* WoH = (unsigned short*)(wsb + OFF_WOH);

  // per-batch workspace: ce 512 KiB + vc 16 MiB + u 16 MiB
  const size_t per_b = (size_t)8*W*4 + (size_t)W*256*4 + (size_t)W*512*2;
  int NB = (int)((ws_size > OFF_CE) ? ((ws_size - OFF_CE) / per_b) : 1);
  if (NB > BATCH) NB = BATCH;
  if (NB < 1) NB = 1;

  float*          ceB = (float*)(wsb + OFF_CE);
  float*          vcB = (float*)(wsb + OFF_CE + (size_t)NB*8*W*4);
  unsigned short* uB  = (unsigned short*)(wsb + OFF_CE + (size_t)NB*8*W*4 + (size_t)NB*W*256*4);

  prep_kernel<<<9, 256, 0, stream>>>(query, Wk, Wkb, rpe, Wv, Wo, wsf, WvH, WoH);

  for (int b0 = 0; b0 < BATCH; b0 += NB) {
    int nb = (BATCH - b0 < NB) ? (BATCH - b0) : NB;
    xv_kernel<<<dim3(256, nb), 512, 0, stream>>>(x, wsf, WvH, tvb, ceB, vcB, b0);
    conv_kernel<<<dim3(256, 4, nb), 256, 0, stream>>>(vcB, ceB, wsf + WS_RPE, uB);
    gemm_out<<<dim3(256, nb), 256, 0, stream>>>(WoH, tob, uB, out, b0);
  }
}

// Round 4
// 469.115 us; speedup vs baseline: 1.0079x; 1.0079x over previous
//
#include <hip/hip_runtime.h>
#include <hip/hip_bf16.h>
#include <math.h>

#define BATCH  8
#define NHEADS 8
#define KW     31
#define W      16384

// ---- workspace byte offsets ----
// floats at base: qWk [256][8] (2048 f), qWk_b [8], rpe_exp [8][31]
#define WS_QWKB 2048
#define WS_RPE  2056
#define OFF_WVH 9216                       // Wv bf16 [256][256]  (131072 B)
#define OFF_WOH (OFF_WVH + 131072)         // Wo bf16 [256][256]
#define OFF_CE  (OFF_WOH + 131072)         // cost_exp fp32 [NB][8][W]
// runtime-sized after OFF_CE:  vc fp32 [NB][W][256]

typedef __attribute__((ext_vector_type(8))) short  short8;
typedef __attribute__((ext_vector_type(4))) float  f32x4;

__device__ __forceinline__ float f4c(const float4& v, int i) {
  switch (i) { case 0: return v.x; case 1: return v.y; case 2: return v.z; default: return v.w; }
}
__device__ __forceinline__ unsigned short f2bf(float f) {
  union { __hip_bfloat16 h; unsigned short u; } cv; cv.h = __float2bfloat16(f); return cv.u;
}
__device__ __forceinline__ float bf2f(unsigned short u) {
  union { __hip_bfloat16 h; unsigned short u; } cv; cv.u = u; return __bfloat162float(cv.h);
}

// ---------------------------------------------------------------- prep ------
// block 0: qWk [256][8], qWk_b[8], rpe_exp; blocks 1-4: Wv->bf16; 5-8: Wo->bf16
__global__ __launch_bounds__(256) void prep_kernel(
    const float* __restrict__ query, const float* __restrict__ Wk,
    const float* __restrict__ Wkb, const float* __restrict__ rpe,
    const float* __restrict__ Wv, const float* __restrict__ Wo,
    float* __restrict__ ws, unsigned short* __restrict__ WvH,
    unsigned short* __restrict__ WoH) {
  int t = threadIdx.x, bid = blockIdx.x;
  if (bid == 0) {
    __shared__ float q_l[256];
    float qv = query[t];
    float ss = qv * qv;
    #pragma unroll
    for (int m = 16; m >= 1; m >>= 1) ss += __shfl_xor(ss, m, 32);
    qv = qv / (sqrtf(ss) + 1e-6f) * 0.17677669529663687f;  // /(norm+1e-6)/sqrt(32)
    q_l[t] = qv;
    __syncthreads();
    const float* wr = Wk + (size_t)t * 256;
    #pragma unroll
    for (int h = 0; h < 8; ++h) {
      float s = 0.f;
      #pragma unroll
      for (int d = 0; d < 32; ++d) s = fmaf(q_l[h*32 + d], wr[h*32 + d], s);
      ws[t*8 + h] = s;
    }
    float pb = Wkb[t] * q_l[t];
    #pragma unroll
    for (int m = 16; m >= 1; m >>= 1) pb += __shfl_xor(pb, m, 32);
    if ((t & 31) == 0) ws[WS_QWKB + (t >> 5)] = pb;
    if (t < NHEADS * KW) ws[WS_RPE + t] = __expf(rpe[t]);
  } else {
    const float* src = (bid <= 4) ? Wv : Wo;
    unsigned short* dst = (bid <= 4) ? WvH : WoH;
    int seg = (bid - 1) & 3;
    int base4 = seg * 4096;   // float4 index base (16384 floats per segment)
    #pragma unroll
    for (int it = 0; it < 16; ++it) {
      int i4 = base4 + t + 256 * it;
      float4 v = ((const float4*)src)[i4];
      ushort4 o;
      o.x = f2bf(v.x); o.y = f2bf(v.y); o.z = f2bf(v.z); o.w = f2bf(v.w);
      ((ushort4*)dst)[i4] = o;
    }
  }
}

// ---------------------------------------------- K2: fused transpose+cost+V --
// 512 threads (8 waves), 64-w tile. 2 blocks/CU (16 waves).
__global__ __launch_bounds__(512, 4) void xv_kernel(
    const float* __restrict__ x, const float* __restrict__ wsf,
    const unsigned short* __restrict__ A,   // WvH bf16 [256][256]
    const float* __restrict__ bias,         // to_v bias
    float* __restrict__ ceout, float* __restrict__ vcout, int b0) {
  __shared__ float xs[64 * 260];    // 66,560 B; row w = 1040 B:
                                    //   phase A: 256 fp32 chans
                                    //   phase B: 256 hi bf16 | 256 lo bf16 (in place)
  __shared__ float cbuf[4 * 576];   // 9,216 B: 4-wave partial rounds, pitch 9
  __shared__ float ceL[512];        // 2,048 B
  __shared__ float biasL[256];      // 1,024 B

  int t = threadIdx.x;
  int bb = blockIdx.y, b = b0 + bb;
  int w0 = blockIdx.x * 64;
  if (t < 256) biasL[t] = bias[t];

  // P1: load x[D][w] tiles, 4x4 register transpose, write xs[w][D] fp32
  {
    int tt = t & 255, db2 = t >> 8;
    int rr = tt >> 4, c2 = tt & 15;
    #pragma unroll
    for (int dd = 0; dd < 2; ++dd) {
      int db = db2 * 2 + dd;
      float4 v0 = *(const float4*)(x + ((size_t)b*256 + db*64 + rr*4 + 0)*W + w0 + c2*4);
      float4 v1 = *(const float4*)(x + ((size_t)b*256 + db*64 + rr*4 + 1)*W + w0 + c2*4);
      float4 v2 = *(const float4*)(x + ((size_t)b*256 + db*64 + rr*4 + 2)*W + w0 + c2*4);
      float4 v3 = *(const float4*)(x + ((size_t)b*256 + db*64 + rr*4 + 3)*W + w0 + c2*4);
      #pragma unroll
      for (int i = 0; i < 4; ++i) {
        float4 tv = make_float4(f4c(v0,i), f4c(v1,i), f4c(v2,i), f4c(v3,i));
        *(float4*)&xs[(c2*4 + i)*260 + db*64 + rr*4] = tv;
      }
    }
  }
  __syncthreads();

  int w = t & 63, q = t >> 6;                 // wave-uniform q (0..7)
  int qu = __builtin_amdgcn_readfirstlane(q); // scalar qWk addressing

  // P2a: pull this thread's 32-chan run into regs, accumulate cost partials
  f32x4 xr[8];
  {
    const float* xrow = &xs[w*260 + qu*32];
    #pragma unroll
    for (int i = 0; i < 8; ++i) xr[i] = *(const f32x4*)(xrow + 4*i);
    float ca[8] = {0,0,0,0,0,0,0,0};
    const float* qkb = wsf + (size_t)qu*256;  // qWk[D][8], D base qu*32
    #pragma unroll
    for (int k4 = 0; k4 < 8; ++k4) {
      const float* qr = qkb + k4*32;
      #pragma unroll
      for (int e = 0; e < 4; ++e) {
        #pragma unroll
        for (int h = 0; h < 8; ++h)
          ca[h] = fmaf(xr[k4][e], qr[e*8 + h], ca[h]);
      }
    }
    if (q < 4) {
      #pragma unroll
      for (int h = 0; h < 8; ++h) cbuf[q*576 + w*9 + h] = ca[h];
    } else {
      #pragma unroll
      for (int h = 0; h < 8; ++h) { asm volatile("" :: "v"(ca[h])); }
    }
    __syncthreads();   // xs fp32 reads done; cbuf round A visible

    // P2b: in-place hi/lo bf16 split (this thread's 32 chans of row w)
    {
      unsigned short* hrow = (unsigned short*)xs + w*520 + qu*32;
      #pragma unroll
      for (int kc = 0; kc < 4; ++kc) {
        short8 hs, ls;
        #pragma unroll
        for (int e = 0; e < 4; ++e) {
          float a0 = xr[2*kc][e], a1 = xr[2*kc+1][e];
          unsigned short h0 = f2bf(a0), h1 = f2bf(a1);
          hs[e]   = (short)h0;  hs[e+4] = (short)h1;
          ls[e]   = (short)f2bf(a0 - bf2f(h0));
          ls[e+4] = (short)f2bf(a1 - bf2f(h1));
        }
        *(short8*)(hrow + 8*kc)       = hs;
        *(short8*)(hrow + 256 + 8*kc) = ls;
      }
    }
    // reduce round A while hi/lo writes are in flight
    float acc0;
    {
      int hR = t >> 6 & 7, wR = t & 63;
      acc0 = cbuf[0*576 + wR*9 + hR] + cbuf[1*576 + wR*9 + hR]
           + cbuf[2*576 + wR*9 + hR] + cbuf[3*576 + wR*9 + hR];
    }
    __syncthreads();   // round-A reads done
    if (q >= 4) {
      #pragma unroll
      for (int h = 0; h < 8; ++h) cbuf[(q-4)*576 + w*9 + h] = ca[h];
    }
    __syncthreads();   // round B visible

    // P3: final reduce, exp, -> ceL + global ce
    {
      int hR = t >> 6 & 7, wR = t & 63;
      float sum = acc0 + cbuf[0*576 + wR*9 + hR] + cbuf[1*576 + wR*9 + hR]
                + cbuf[2*576 + wR*9 + hR] + cbuf[3*576 + wR*9 + hR]
                + wsf[WS_QWKB + hR];
      float ce = __expf(sum);
      ceL[hR*64 + wR] = ce;
      ceout[((size_t)bb*8 + hR)*W + w0 + wR] = ce;
    }
  }
  __syncthreads();

  // P4: MFMA GEMM  v[256 o][64 w] = Wv . x  (hi + lo)
  int wid = t >> 6, quad = (t >> 4) & 3, m = t & 15;
  f32x4 acc[2][4];
  #pragma unroll
  for (int j = 0; j < 2; ++j)
    #pragma unroll
    for (int c = 0; c < 4; ++c) acc[j][c] = (f32x4){0.f, 0.f, 0.f, 0.f};

  const unsigned short* xsu = (const unsigned short*)xs;
  #pragma unroll
  for (int kk = 0; kk < 8; ++kk) {
    int ko = kk*32 + quad*8;
    short8 a0 = *(const short8*)(A + (size_t)(32*wid + m)*256 + ko);
    short8 a1 = *(const short8*)(A + (size_t)(32*wid + 16 + m)*256 + ko);
    #pragma unroll
    for (int c = 0; c < 4; ++c) {
      int rw = 16*c + m;
      short8 bh = *(const short8*)(xsu + rw*520 + ko);
      short8 bl = *(const short8*)(xsu + rw*520 + 256 + ko);
      acc[0][c] = __builtin_amdgcn_mfma_f32_16x16x32_bf16(a0, bh, acc[0][c], 0, 0, 0);
      acc[0][c] = __builtin_amdgcn_mfma_f32_16x16x32_bf16(a0, bl, acc[0][c], 0, 0, 0);
      acc[1][c] = __builtin_amdgcn_mfma_f32_16x16x32_bf16(a1, bh, acc[1][c], 0, 0, 0);
      acc[1][c] = __builtin_amdgcn_mfma_f32_16x16x32_bf16(a1, bl, acc[1][c], 0, 0, 0);
    }
  }
  __syncthreads();   // B-reads of xs done before epilogue reuses it

  // P5: vc = ce[h][w] * (v + bias) -> xs [w][256 o] pitch 260
  #pragma unroll
  for (int j = 0; j < 2; ++j) {
    int ob = 32*wid + 16*j + 4*quad;
    #pragma unroll
    for (int c = 0; c < 4; ++c) {
      int wc = 16*c + m;
      float ce = ceL[wid*64 + wc];   // head == wid
      f32x4 r;
      #pragma unroll
      for (int i = 0; i < 4; ++i) r[i] = (acc[j][c][i] + biasL[ob + i]) * ce;
      *(f32x4*)(xs + wc*260 + ob) = r;
    }
  }
  __syncthreads();
  // linear coalesced copy-out
  {
    float* vg = vcout + ((size_t)bb*W + w0)*256;
    #pragma unroll
    for (int it = 0; it < 8; ++it) {
      int idx = t + 512*it;                 // 4096 x 16B = 64 KiB
      int row = idx >> 6, c4 = (idx & 63)*4;
      f32x4 v = *(const f32x4*)(xs + row*260 + c4);
      *(f32x4*)(vg + (size_t)idx*4) = v;
    }
  }
}

// ------------------------------------- K3: fused conv + Wo GEMM (out) -------
// per (32-w tile, batch), 512 threads (8 waves), LDS 47.8 KB -> 3 blocks/CU.
// Loop over 8 head-tiles (32 chans): stage vc halo [62][32] fp32, conv K=31,
// divide by sum_c, hi/lo bf16 split -> LDS ubuf. Then out = Wo . u + bias,
// assembled in LDS, dense line-aligned stores. u never touches HBM.
__global__ __launch_bounds__(512, 6) void cg_kernel(
    const float* __restrict__ vc, const float* __restrict__ costexp,
    const float* __restrict__ rpe_ws, const unsigned short* __restrict__ A,
    const float* __restrict__ bias, float* __restrict__ outp, int b0) {
  __shared__ __align__(16) float vcl[62 * 36];            //  8,928 B
  __shared__ __align__(16) unsigned short ubuf[2][32*264];// 33,792 B (hi, lo)
  __shared__ float cel[8 * 64];                           //  2,048 B (62 used)
  __shared__ float rcl[8 * 32];                           //  1,024 B
  __shared__ float rpel[8 * 32];                          //  1,024 B
  __shared__ float biasL[256];                            //  1,024 B

  int t = threadIdx.x;
  int bb = blockIdx.y;
  // XCD-chunked swizzle: 512 w-tiles/batch -> 64 consecutive tiles per XCD
  int tx = blockIdx.x;
  int tile = ((tx & 7) << 6) | (tx >> 3);
  int w0 = tile * 32;

  // prologue staging
  if (t < 256) {
    biasL[t] = bias[t];
    int h = t >> 5, k = t & 31;
    rpel[t] = (k < KW) ? rpe_ws[h*KW + k] : 0.f;
  }
  {
    int h = t >> 6, c = t & 63;
    if (c < 62) {
      int gw = w0 - 15 + c;
      cel[h*64 + c] = (gw >= 0 && gw < W) ? costexp[((size_t)bb*8 + h)*W + gw] : 0.f;
    }
  }
  __syncthreads();
  // rc = 1/sum_c  (order identical to previous conv kernel: k ascending)
  if (t < 256) {
    int h = t >> 5, w = t & 31;
    float acc = 0.f;
    #pragma unroll
    for (int k = 0; k < KW; ++k) acc = fmaf(rpel[h*32 + k], cel[h*64 + w + k], acc);
    rcl[t] = 1.0f / acc;
  }

  int wv = t >> 4, p = t & 15;   // conv mapping: 1 w x chan-pair (2p,2p+1)
  for (int q = 0; q < 8; ++q) {  // head-tile q = head index, chans 32q..32q+31
    // stage vcl [62 rows][32 chans] fp32 (pitch 36)
    if (t < 496) {
      int r = t >> 3, c4 = (t & 7) * 4;
      int gw = w0 - 15 + r;
      float4 v = make_float4(0.f, 0.f, 0.f, 0.f);
      if (gw >= 0 && gw < W)
        v = *(const float4*)(vc + ((size_t)bb*W + gw)*256 + q*32 + c4);
      *(float4*)&vcl[r*36 + c4] = v;
    }
    __syncthreads();
    // conv (k ascending, same fp32 order as before) + divide + hi/lo split
    {
      float ax = 0.f, ay = 0.f;
      #pragma unroll
      for (int k = 0; k < KW; ++k) {
        float rpk = rpel[q*32 + k];
        float2 v = *(const float2*)&vcl[(wv + k)*36 + 2*p];
        ax = fmaf(rpk, v.x, ax);
        ay = fmaf(rpk, v.y, ay);
      }
      float rc = rcl[q*32 + wv];
      float ux = ax * rc, uy = ay * rc;
      unsigned short hx = f2bf(ux), hy = f2bf(uy);
      unsigned short lx = f2bf(ux - bf2f(hx)), ly = f2bf(uy - bf2f(hy));
      ushort2 hv; hv.x = hx; hv.y = hy;
      ushort2 lv; lv.x = lx; lv.y = ly;
      *(ushort2*)&ubuf[0][wv*264 + q*32 + 2*p] = hv;
      *(ushort2*)&ubuf[1][wv*264 + q*32 + 2*p] = lv;
    }
    __syncthreads();   // vcl reads done before next stage; ubuf visible at end
  }

  // MFMA: out[256 o][32 w] = Wo . u (hi then lo), accumulation order preserved
  int wid = t >> 6, quad = (t >> 4) & 3, m = t & 15;
  f32x4 acc[2][2];
  #pragma unroll
  for (int j = 0; j < 2; ++j)
    #pragma unroll
    for (int c = 0; c < 2; ++c) acc[j][c] = (f32x4){0.f, 0.f, 0.f, 0.f};

  #pragma unroll
  for (int pass = 0; pass < 2; ++pass) {
    const unsigned short* bsrc = ubuf[pass];
    #pragma unroll
    for (int kk = 0; kk < 8; ++kk) {
      int ko = kk*32 + quad*8;
      short8 a0 = *(const short8*)(A + (size_t)(32*wid + m)*256 + ko);
      short8 a1 = *(const short8*)(A + (size_t)(32*wid + 16 + m)*256 + ko);
      #pragma unroll
      for (int c = 0; c < 2; ++c) {
        short8 bv = *(const short8*)(bsrc + (16*c + m)*264 + ko);
        acc[0][c] = __builtin_amdgcn_mfma_f32_16x16x32_bf16(a0, bv, acc[0][c], 0, 0, 0);
        acc[1][c] = __builtin_amdgcn_mfma_f32_16x16x32_bf16(a1, bv, acc[1][c], 0, 0, 0);
      }
    }
  }
  __syncthreads();   // ubuf reads done; reuse as fp32 assembly [256 o][32 w]

  float* outs = (float*)ubuf;     // 256*32*4 = 32,768 B <= 33,792 B
  #pragma unroll
  for (int j = 0; j < 2; ++j) {
    int ob = 32*wid + 16*j + 4*quad;
    #pragma unroll
    for (int c = 0; c < 2; ++c) {
      int w = 16*c + m;
      #pragma unroll
      for (int i = 0; i < 4; ++i)
        outs[(ob + i)*32 + w] = acc[j][c][i] + biasL[ob + i];
    }
  }
  __syncthreads();
  // dense stores: per wave-instr 8 rows x 128 B full lines
  {
    float* og = outp + (size_t)(b0 + bb)*256*W + w0;
    #pragma unroll
    for (int it = 0; it < 4; ++it) {
      int idx = t + 512*it;          // 2048 f32x4
      int o = idx >> 3, c4 = (idx & 7)*4;
      f32x4 v = *(const f32x4*)(outs + o*32 + c4);
      *(f32x4*)(og + (size_t)o*W + c4) = v;
    }
  }
}

// ---------------------------------------------------------------- launch ----
extern "C" void kernel_launch(void* const* d_in, const int* in_sizes, int n_in,
                              void* d_out, int out_size, void* d_ws, size_t ws_size,
                              hipStream_t stream) {
  const float* x     = (const float*)d_in[0];
  const float* query = (const float*)d_in[1];
  const float* Wk    = (const float*)d_in[2];
  const float* Wkb   = (const float*)d_in[3];
  const float* rpe   = (const float*)d_in[4];
  const float* Wv    = (const float*)d_in[5];
  const float* tvb   = (const float*)d_in[6];
  const float* Wo    = (const float*)d_in[7];
  const float* tob   = (const float*)d_in[8];
  float* out = (float*)d_out;
  char* wsb  = (char*)d_ws;
  float* wsf = (float*)d_ws;

  unsigned short* WvH = (unsigned short*)(wsb + OFF_WVH);
  unsigned short* WoH = (unsigned short*)(wsb + OFF_WOH);

  // per-batch workspace: ce 512 KiB + vc 16 MiB
  const size_t per_b = (size_t)8*W*4 + (size_t)W*256*4;
  int NB = (int)((ws_size > OFF_CE) ? ((ws_size - OFF_CE) / per_b) : 1);
  if (NB > BATCH) NB = BATCH;
  if (NB < 1) NB = 1;

  float* ceB = (float*)(wsb + OFF_CE);
  float* vcB = (float*)(wsb + OFF_CE + (size_t)NB*8*W*4);

  prep_kernel<<<9, 256, 0, stream>>>(query, Wk, Wkb, rpe, Wv, Wo, wsf, WvH, WoH);

  for (int b0 = 0; b0 < BATCH; b0 += NB) {
    int nb = (BATCH - b0 < NB) ? (BATCH - b0) : NB;
    xv_kernel<<<dim3(256, nb), 512, 0, stream>>>(x, wsf, WvH, tvb, ceB, vcB, b0);
    cg_kernel<<<dim3(512, nb), 512, 0, stream>>>(vcB, ceB, wsf + WS_RPE, WoH, tob, out, b0);
  }
}

// Round 5
// 419.508 us; speedup vs baseline: 1.1270x; 1.1183x over previous
//
#include <hip/hip_runtime.h>
#include <hip/hip_bf16.h>
#include <math.h>

#define BATCH  8
#define NHEADS 8
#define KW     31
#define W      16384

// ---- workspace byte offsets ----
// floats at base: qWk [256][8] (2048 f), qWk_b [8], rpe_exp [8][31]
#define WS_QWKB 2048
#define WS_RPE  2056
#define OFF_WVH 9216                       // Wv bf16 [256][256]  (131072 B)
#define OFF_WOH (OFF_WVH + 131072)         // Wo bf16 [256][256]
#define OFF_CE  (OFF_WOH + 131072)         // cost_exp fp32 [NB][8][W]
// runtime-sized after OFF_CE:  vc fp32 [NB][W][256]

typedef __attribute__((ext_vector_type(8))) short  short8;
typedef __attribute__((ext_vector_type(4))) float  f32x4;

__device__ __forceinline__ float f4c(const float4& v, int i) {
  switch (i) { case 0: return v.x; case 1: return v.y; case 2: return v.z; default: return v.w; }
}
__device__ __forceinline__ unsigned short f2bf(float f) {
  union { __hip_bfloat16 h; unsigned short u; } cv; cv.h = __float2bfloat16(f); return cv.u;
}
__device__ __forceinline__ float bf2f(unsigned short u) {
  union { __hip_bfloat16 h; unsigned short u; } cv; cv.u = u; return __bfloat162float(cv.h);
}

// ---------------------------------------------------------------- prep ------
// block 0: qWk [256][8], qWk_b[8], rpe_exp; blocks 1-4: Wv->bf16; 5-8: Wo->bf16
__global__ __launch_bounds__(256) void prep_kernel(
    const float* __restrict__ query, const float* __restrict__ Wk,
    const float* __restrict__ Wkb, const float* __restrict__ rpe,
    const float* __restrict__ Wv, const float* __restrict__ Wo,
    float* __restrict__ ws, unsigned short* __restrict__ WvH,
    unsigned short* __restrict__ WoH) {
  int t = threadIdx.x, bid = blockIdx.x;
  if (bid == 0) {
    __shared__ float q_l[256];
    float qv = query[t];
    float ss = qv * qv;
    #pragma unroll
    for (int m = 16; m >= 1; m >>= 1) ss += __shfl_xor(ss, m, 32);
    qv = qv / (sqrtf(ss) + 1e-6f) * 0.17677669529663687f;  // /(norm+1e-6)/sqrt(32)
    q_l[t] = qv;
    __syncthreads();
    const float* wr = Wk + (size_t)t * 256;
    #pragma unroll
    for (int h = 0; h < 8; ++h) {
      float s = 0.f;
      #pragma unroll
      for (int d = 0; d < 32; ++d) s = fmaf(q_l[h*32 + d], wr[h*32 + d], s);
      ws[t*8 + h] = s;
    }
    float pb = Wkb[t] * q_l[t];
    #pragma unroll
    for (int m = 16; m >= 1; m >>= 1) pb += __shfl_xor(pb, m, 32);
    if ((t & 31) == 0) ws[WS_QWKB + (t >> 5)] = pb;
    if (t < NHEADS * KW) ws[WS_RPE + t] = __expf(rpe[t]);
  } else {
    const float* src = (bid <= 4) ? Wv : Wo;
    unsigned short* dst = (bid <= 4) ? WvH : WoH;
    int seg = (bid - 1) & 3;
    int base4 = seg * 4096;   // float4 index base (16384 floats per segment)
    #pragma unroll
    for (int it = 0; it < 16; ++it) {
      int i4 = base4 + t + 256 * it;
      float4 v = ((const float4*)src)[i4];
      ushort4 o;
      o.x = f2bf(v.x); o.y = f2bf(v.y); o.z = f2bf(v.z); o.w = f2bf(v.w);
      ((ushort4*)dst)[i4] = o;
    }
  }
}

// ---------------------------------------------- K2: fused transpose+cost+V --
// 256 threads (measured-good round-1 structure), 64-w tile, 2 blocks/CU.
// Only change vs round-1: linear coalesced vc copy-out (removes 2.3x write amp).
__global__ __launch_bounds__(256, 2) void xv_kernel(
    const float* __restrict__ x, const float* __restrict__ wsf,
    const unsigned short* __restrict__ A,   // WvH bf16 [256][256]
    const float* __restrict__ bias,         // to_v bias
    float* __restrict__ ceout, float* __restrict__ vcout, int b0) {
  __shared__ float xs[64 * 260];    // 66,560 B; row w = 1040 B:
                                    //   phase A: 256 fp32 chans
                                    //   phase B: 256 hi bf16 | 256 lo bf16 (in place)
  __shared__ float cbuf[2048];      // cost partial exchange
  __shared__ float ceL[512];        // ce[h][w]
  __shared__ float biasL[256];

  int t = threadIdx.x;
  int bb = blockIdx.y, b = b0 + bb;
  int w0 = blockIdx.x * 64;
  biasL[t] = bias[t];

  // P1: load x[D][w] tiles, 4x4 register transpose, write xs[w][D] fp32
  {
    int rr = t >> 4, c2 = t & 15;
    #pragma unroll
    for (int db = 0; db < 4; ++db) {
      float4 v0 = *(const float4*)(x + ((size_t)b*256 + db*64 + rr*4 + 0)*W + w0 + c2*4);
      float4 v1 = *(const float4*)(x + ((size_t)b*256 + db*64 + rr*4 + 1)*W + w0 + c2*4);
      float4 v2 = *(const float4*)(x + ((size_t)b*256 + db*64 + rr*4 + 2)*W + w0 + c2*4);
      float4 v3 = *(const float4*)(x + ((size_t)b*256 + db*64 + rr*4 + 3)*W + w0 + c2*4);
      #pragma unroll
      for (int i = 0; i < 4; ++i) {
        float4 tv = make_float4(f4c(v0,i), f4c(v1,i), f4c(v2,i), f4c(v3,i));
        *(float4*)&xs[(c2*4 + i)*260 + db*64 + rr*4] = tv;
      }
    }
  }
  __syncthreads();

  int w = t & 63, q = t >> 6;
  int qu = __builtin_amdgcn_readfirstlane(q);

  // P2a: pull this thread's 64-chan run into regs, accumulate cost partials
  f32x4 xr[16];
  {
    const float* xrow = &xs[w*260 + qu*64];
    #pragma unroll
    for (int i = 0; i < 16; ++i) xr[i] = *(const f32x4*)(xrow + 4*i);
    float ca[8] = {0,0,0,0,0,0,0,0};
    const float* qkb = wsf + (size_t)qu*64*8;
    #pragma unroll
    for (int k8 = 0; k8 < 8; ++k8) {
      const float* qr = qkb + 64*k8;
      #pragma unroll
      for (int e = 0; e < 4; ++e) {
        #pragma unroll
        for (int h = 0; h < 8; ++h) {
          ca[h] = fmaf(xr[2*k8][e],   qr[e*8 + h],     ca[h]);
          ca[h] = fmaf(xr[2*k8+1][e], qr[(e+4)*8 + h], ca[h]);
        }
      }
    }
    #pragma unroll
    for (int h = 0; h < 8; ++h) cbuf[t*8 + h] = ca[h];
  }
  __syncthreads();   // all fp32 reads of xs done before in-place overwrite

  // P2b: in-place hi/lo bf16 split: row w -> hi[256] @ +0, lo[256] @ +512 B
  {
    unsigned short* hrow = (unsigned short*)xs + w*520 + qu*64;
    #pragma unroll
    for (int k8 = 0; k8 < 8; ++k8) {
      short8 hs, ls;
      #pragma unroll
      for (int e = 0; e < 4; ++e) {
        float a0 = xr[2*k8][e], a1 = xr[2*k8+1][e];
        unsigned short h0 = f2bf(a0), h1 = f2bf(a1);
        hs[e]   = (short)h0;  hs[e+4] = (short)h1;
        ls[e]   = (short)f2bf(a0 - bf2f(h0));
        ls[e+4] = (short)f2bf(a1 - bf2f(h1));
      }
      *(short8*)(hrow + 8*k8)       = hs;
      *(short8*)(hrow + 256 + 8*k8) = ls;
    }
  }
  __syncthreads();

  // P3: reduce cost partials, exp, -> ceL + global ce
  #pragma unroll
  for (int s = 0; s < 2; ++s) {
    int idx = t + 256*s;
    int h = idx >> 6, ww = idx & 63;
    float sum = cbuf[ww*8 + h] + cbuf[(64+ww)*8 + h] + cbuf[(128+ww)*8 + h]
              + cbuf[(192+ww)*8 + h] + wsf[WS_QWKB + h];
    float ce = __expf(sum);
    ceL[h*64 + ww] = ce;
    ceout[((size_t)bb*8 + h)*W + w0 + ww] = ce;
  }
  __syncthreads();

  // P4: MFMA GEMM  v[256 o][64 w] = Wv . x  (hi + lo)
  int wid = t >> 6, quad = (t >> 4) & 3, m = t & 15;
  f32x4 acc[4][4];
  #pragma unroll
  for (int j = 0; j < 4; ++j)
    #pragma unroll
    for (int c = 0; c < 4; ++c) acc[j][c] = (f32x4){0.f, 0.f, 0.f, 0.f};

  const unsigned short* xsu = (const unsigned short*)xs;
  #pragma unroll
  for (int kk = 0; kk < 8; ++kk) {
    int ko = kk*32 + quad*8;
    short8 a[4], bh[4], bl[4];
    #pragma unroll
    for (int j = 0; j < 4; ++j)
      a[j] = *(const short8*)(A + (size_t)(64*wid + 16*j + m)*256 + ko);
    #pragma unroll
    for (int c = 0; c < 4; ++c) {
      int rw = 16*c + m;
      bh[c] = *(const short8*)(xsu + rw*520 + ko);
      bl[c] = *(const short8*)(xsu + rw*520 + 256 + ko);
    }
    #pragma unroll
    for (int j = 0; j < 4; ++j)
      #pragma unroll
      for (int c = 0; c < 4; ++c) {
        acc[j][c] = __builtin_amdgcn_mfma_f32_16x16x32_bf16(a[j], bh[c], acc[j][c], 0, 0, 0);
        acc[j][c] = __builtin_amdgcn_mfma_f32_16x16x32_bf16(a[j], bl[c], acc[j][c], 0, 0, 0);
      }
  }
  __syncthreads();   // B-reads of xs done before epilogue reuses it

  // P5: vc = ce[h][w] * (v + bias) -> xs [w][256 o] pitch 260
  #pragma unroll
  for (int j = 0; j < 4; ++j) {
    int ob = 64*wid + 16*j + 4*quad;
    int h = (64*wid + 16*j) >> 5;
    #pragma unroll
    for (int c = 0; c < 4; ++c) {
      int wc = 16*c + m;
      float ce = ceL[h*64 + wc];
      f32x4 r;
      #pragma unroll
      for (int i = 0; i < 4; ++i) r[i] = (acc[j][c][i] + biasL[ob + i]) * ce;
      *(f32x4*)(xs + wc*260 + ob) = r;
    }
  }
  __syncthreads();
  // linear coalesced copy-out: wave writes contiguous 1 KiB per instruction
  {
    float* vg = vcout + ((size_t)bb*W + w0)*256;
    #pragma unroll
    for (int it = 0; it < 16; ++it) {
      int idx = t + 256*it;                 // 4096 x 16B = 64 KiB
      int row = idx >> 6, c4 = (idx & 63)*4;
      f32x4 v = *(const f32x4*)(xs + row*260 + c4);
      *(f32x4*)(vg + (size_t)idx*4) = v;
    }
  }
}

// ------------------------------------- K3: fused conv + Wo GEMM (out) -------
// per (32-w tile, batch), 512 threads (8 waves), LDS 72.2 KB -> 2 blocks/CU.
// Conv as register sliding window over 2 channel-halves [62][128] fp32:
// thread owns 2 w x 4 chans, 32 b128 reads per half (4 reads/output).
// u -> LDS ubuf (hi|lo), then out = Wo . u + bias, dense full-line stores.
__global__ __launch_bounds__(512, 4) void cg_kernel(
    const float* __restrict__ vc, const float* __restrict__ costexp,
    const float* __restrict__ rpe_ws, const unsigned short* __restrict__ A,
    const float* __restrict__ bias, float* __restrict__ outp, int b0) {
  __shared__ __align__(16) float vcl[63 * 132];            // 33,264 B (62 rows used)
  __shared__ __align__(16) unsigned short ubuf[32 * 528];  // 33,792 B [w][hi256|lo256|pad]
  __shared__ float cel[8 * 64];                            //  2,048 B (62 used/row)
  __shared__ float rcl[8 * 32];                            //  1,024 B
  __shared__ float rpel[8 * 32];                           //  1,024 B
  __shared__ float biasL[256];                             //  1,024 B

  int t = threadIdx.x;
  int bb = blockIdx.y;
  // XCD-chunked swizzle: 512 w-tiles/batch -> 64 consecutive tiles per XCD
  int tx = blockIdx.x;
  int tile = ((tx & 7) << 6) | (tx >> 3);
  int w0 = tile * 32;

  // prologue staging
  if (t < 256) {
    biasL[t] = bias[t];
    int h = t >> 5, k = t & 31;
    rpel[t] = (k < KW) ? rpe_ws[h*KW + k] : 0.f;
  }
  {
    int h = t >> 6, c = t & 63;
    if (c < 62) {
      int gw = w0 - 15 + c;
      cel[h*64 + c] = (gw >= 0 && gw < W) ? costexp[((size_t)bb*8 + h)*W + gw] : 0.f;
    }
  }
  __syncthreads();
  // rc = 1/sum_c  (k ascending, same fp32 order as always)
  if (t < 256) {
    int h = t >> 5, w = t & 31;
    float acc = 0.f;
    #pragma unroll
    for (int k = 0; k < KW; ++k) acc = fmaf(rpel[h*32 + k], cel[h*64 + w + k], acc);
    rcl[t] = 1.0f / acc;
  }

  // conv thread mapping: g = w-group (2 w), p4 = float4 chan group (4 chans)
  int g = t >> 5, p4 = t & 31;
  for (int half = 0; half < 2; ++half) {
    // stage vcl [62 rows][128 chans] fp32 (pitch 132)
    #pragma unroll
    for (int it = 0; it < 4; ++it) {
      int idx = t + 512*it;
      int r = idx >> 5, fq = idx & 31;
      if (r < 62) {
        int gw = w0 - 15 + r;
        float4 v = make_float4(0.f, 0.f, 0.f, 0.f);
        if (gw >= 0 && gw < W)
          v = *(const float4*)(vc + ((size_t)bb*W + gw)*256 + half*128 + fq*4);
        *(float4*)&vcl[r*132 + fq*4] = v;
      }
    }
    __syncthreads();   // vcl (+rcl first iter) visible; prior conv reads done

    {
      int h = 4*half + (p4 >> 3);     // head of this chan group
      float rp[KW];
      #pragma unroll
      for (int k = 0; k < KW; ++k) rp[k] = rpel[h*32 + k];

      f32x4 a0 = (f32x4){0.f,0.f,0.f,0.f}, a1 = (f32x4){0.f,0.f,0.f,0.f};
      #pragma unroll
      for (int s = 0; s < 32; ++s) {
        f32x4 v = *(const f32x4*)&vcl[(2*g + s)*132 + 4*p4];
        if (s < KW) {              // w = 2g,   k = s   (ascending)
          #pragma unroll
          for (int e = 0; e < 4; ++e) a0[e] = fmaf(rp[s], v[e], a0[e]);
        }
        if (s >= 1) {              // w = 2g+1, k = s-1 (ascending)
          #pragma unroll
          for (int e = 0; e < 4; ++e) a1[e] = fmaf(rp[s-1], v[e], a1[e]);
        }
      }
      // divide + hi/lo split -> ubuf
      float rc0 = rcl[h*32 + 2*g], rc1 = rcl[h*32 + 2*g + 1];
      ushort4 h0v, l0v, h1v, l1v;
      #pragma unroll
      for (int e = 0; e < 4; ++e) {
        float u0 = a0[e] * rc0, u1 = a1[e] * rc1;
        unsigned short hh0 = f2bf(u0), hh1 = f2bf(u1);
        ((unsigned short*)&h0v)[e] = hh0;
        ((unsigned short*)&l0v)[e] = f2bf(u0 - bf2f(hh0));
        ((unsigned short*)&h1v)[e] = hh1;
        ((unsigned short*)&l1v)[e] = f2bf(u1 - bf2f(hh1));
      }
      int cbase = half*128 + 4*p4;
      *(ushort4*)&ubuf[(2*g    )*528 + cbase]       = h0v;
      *(ushort4*)&ubuf[(2*g    )*528 + 256 + cbase] = l0v;
      *(ushort4*)&ubuf[(2*g + 1)*528 + cbase]       = h1v;
      *(ushort4*)&ubuf[(2*g + 1)*528 + 256 + cbase] = l1v;
    }
    __syncthreads();   // ubuf visible; vcl reads done before restage
  }

  // MFMA: out[256 o][32 w] = Wo . u (hi then lo)
  int wid = t >> 6, quad = (t >> 4) & 3, m = t & 15;
  f32x4 acc[2][2];
  #pragma unroll
  for (int j = 0; j < 2; ++j)
    #pragma unroll
    for (int c = 0; c < 2; ++c) acc[j][c] = (f32x4){0.f, 0.f, 0.f, 0.f};

  #pragma unroll
  for (int pass = 0; pass < 2; ++pass) {
    #pragma unroll
    for (int kk = 0; kk < 8; ++kk) {
      int ko = kk*32 + quad*8;
      short8 a0 = *(const short8*)(A + (size_t)(32*wid + m)*256 + ko);
      short8 a1 = *(const short8*)(A + (size_t)(32*wid + 16 + m)*256 + ko);
      #pragma unroll
      for (int c = 0; c < 2; ++c) {
        short8 bv = *(const short8*)(ubuf + (16*c + m)*528 + pass*256 + ko);
        acc[0][c] = __builtin_amdgcn_mfma_f32_16x16x32_bf16(a0, bv, acc[0][c], 0, 0, 0);
        acc[1][c] = __builtin_amdgcn_mfma_f32_16x16x32_bf16(a1, bv, acc[1][c], 0, 0, 0);
      }
    }
  }

  // epilogue assembly in LDS over vcl region (conv reads long done)
  float* outs = (float*)vcl;      // 256*32*4 = 32,768 B <= 33,264 B
  #pragma unroll
  for (int j = 0; j < 2; ++j) {
    int ob = 32*wid + 16*j + 4*quad;
    #pragma unroll
    for (int c = 0; c < 2; ++c) {
      int w = 16*c + m;
      #pragma unroll
      for (int i = 0; i < 4; ++i)
        outs[(ob + i)*32 + w] = acc[j][c][i] + biasL[ob + i];
    }
  }
  __syncthreads();
  // dense stores: per wave-instr 8 rows x 128 B full lines
  {
    float* og = outp + (size_t)(b0 + bb)*256*W + w0;
    #pragma unroll
    for (int it = 0; it < 4; ++it) {
      int idx = t + 512*it;          // 2048 f32x4
      int o = idx >> 3, c4 = (idx & 7)*4;
      f32x4 v = *(const f32x4*)(outs + o*32 + c4);
      *(f32x4*)(og + (size_t)o*W + c4) = v;
    }
  }
}

// ---------------------------------------------------------------- launch ----
extern "C" void kernel_launch(void* const* d_in, const int* in_sizes, int n_in,
                              void* d_out, int out_size, void* d_ws, size_t ws_size,
                              hipStream_t stream) {
  const float* x     = (const float*)d_in[0];
  const float* query = (const float*)d_in[1];
  const float* Wk    = (const float*)d_in[2];
  const float* Wkb   = (const float*)d_in[3];
  const float* rpe   = (const float*)d_in[4];
  const float* Wv    = (const float*)d_in[5];
  const float* tvb   = (const float*)d_in[6];
  const float* Wo    = (const float*)d_in[7];
  const float* tob   = (const float*)d_in[8];
  float* out = (float*)d_out;
  char* wsb  = (char*)d_ws;
  float* wsf = (float*)d_ws;

  unsigned short* WvH = (unsigned short*)(wsb + OFF_WVH);
  unsigned short* WoH = (unsigned short*)(wsb + OFF_WOH);

  // per-batch workspace: ce 512 KiB + vc 16 MiB
  const size_t per_b = (size_t)8*W*4 + (size_t)W*256*4;
  int NB = (int)((ws_size > OFF_CE) ? ((ws_size - OFF_CE) / per_b) : 1);
  if (NB > BATCH) NB = BATCH;
  if (NB < 1) NB = 1;

  float* ceB = (float*)(wsb + OFF_CE);
  float* vcB = (float*)(wsb + OFF_CE + (size_t)NB*8*W*4);

  prep_kernel<<<9, 256, 0, stream>>>(query, Wk, Wkb, rpe, Wv, Wo, wsf, WvH, WoH);

  for (int b0 = 0; b0 < BATCH; b0 += NB) {
    int nb = (BATCH - b0 < NB) ? (BATCH - b0) : NB;
    xv_kernel<<<dim3(256, nb), 256, 0, stream>>>(x, wsf, WvH, tvb, ceB, vcB, b0);
    cg_kernel<<<dim3(512, nb), 512, 0, stream>>>(vcB, ceB, wsf + WS_RPE, WoH, tob, out, b0);
  }
}